// Round 1
// baseline (2198.370 us; speedup 1.0000x reference)
//
#include <hip/hip_runtime.h>

namespace {
constexpr int kB  = 1024;
constexpr int kT  = 512;
constexpr int kNL = 128;
constexpr float kFreq = 3.0f;
constexpr size_t kOffP = (size_t)2 * kT * kB;          // start of traj_p
constexpr size_t kOffL = kOffP + (size_t)kT * kB;      // start of logpt
}

__global__ __launch_bounds__(64, 1) void ode_seq_kernel(
    const float* __restrict__ latent,
    const float* __restrict__ tarr,
    const float* __restrict__ W_l2d,
    const float* __restrict__ b_l2d,
    const float* __restrict__ W1,
    const float* __restrict__ b1,
    const float* __restrict__ W2,
    const float* __restrict__ b2,
    const float* __restrict__ W3,
    const float* __restrict__ b3,
    const float* __restrict__ W_obs,
    const float* __restrict__ b_obs,
    float* __restrict__ out)
{
    const int row  = blockIdx.x;
    const int lane = threadIdx.x;
    const int c    = lane & 31;   // output column for GEMM1
    const int kh   = lane >> 5;   // k-half for GEMM1 (0: pos part, 1: vel part)

    __shared__ __align__(16) float s_lds[128];   // state broadcast buffer
    __shared__ __align__(16) float h1_lds[32];
    __shared__ __align__(16) float h2_lds[64];
    __shared__ float dts[kT];                    // 511 used

    for (int i = lane; i < kT - 1; i += 64) dts[i] = tarr[i + 1] - tarr[i];

    // stage latent row into LDS (reused for l1 precompute and y0)
    s_lds[lane]      = latent[row * kNL + lane];
    s_lds[64 + lane] = latent[row * kNL + 64 + lane];
    __syncthreads();

    // ---- weights into registers (prescaled by FREQ where they feed a cos) ----
    float w1[64], w2[32], w3[64];
    #pragma unroll
    for (int j = 0; j < 64; ++j) w1[j] = kFreq * W1[(kh * 64 + j) * 32 + c];
    #pragma unroll
    for (int j = 0; j < 32; ++j) w2[j] = kFreq * W2[j * 64 + lane];
    #pragma unroll
    for (int j = 0; j < 64; ++j) w3[j] = W3[j * 64 + lane];

    const float wo0 = W_obs[lane * 3 + 0];
    const float wo1 = W_obs[lane * 3 + 1];
    const float wo2 = W_obs[lane * 3 + 2];
    const float bo0 = b_obs[0], bo1 = b_obs[1], bo2 = b_obs[2];

    // ---- time-invariant latent contribution to layer-1 preact (+ b1) ----
    float l1p = 0.f;
    #pragma unroll 8
    for (int j = 0; j < 64; ++j)
        l1p = fmaf(s_lds[kh * 64 + j], W1[(128 + kh * 64 + j) * 32 + c], l1p);
    l1p += __shfl_xor(l1p, 32);
    const float l1init = (kh == 0) ? kFreq * (l1p + b1[c]) : 0.f;
    const float b2s = kFreq * b2[lane];
    const float b3s = b3[lane];

    // ---- y0 = latent @ W_l2d + b_l2d ----
    float pos = b_l2d[lane];
    float vel = b_l2d[64 + lane];
    #pragma unroll 4
    for (int k = 0; k < 128; ++k) {
        const float lv = s_lds[k];
        pos = fmaf(lv, W_l2d[k * 128 + lane], pos);
        vel = fmaf(lv, W_l2d[k * 128 + 64 + lane], vel);
    }

    const float4* __restrict__ s4  = reinterpret_cast<const float4*>(s_lds);
    const float4* __restrict__ h14 = reinterpret_cast<const float4*>(h1_lds);
    const float4* __restrict__ h24 = reinterpret_cast<const float4*>(h2_lds);

    // dyn: (p, v) per-lane state elements -> acceleration element for this lane
    auto dyn = [&](float p, float v) -> float {
        __syncthreads();                 // previous readers of s_lds done
        s_lds[lane]      = p;
        s_lds[64 + lane] = v;
        __syncthreads();
        // GEMM1: half-wave kh sums its 64-k slice for output column c
        float acc = l1init;
        #pragma unroll
        for (int jj = 0; jj < 16; ++jj) {
            const float4 sv = s4[kh * 16 + jj];
            acc = fmaf(sv.x, w1[4 * jj + 0], acc);
            acc = fmaf(sv.y, w1[4 * jj + 1], acc);
            acc = fmaf(sv.z, w1[4 * jj + 2], acc);
            acc = fmaf(sv.w, w1[4 * jj + 3], acc);
        }
        acc += __shfl_xor(acc, 32);      // combine k-halves
        const float h1 = cosf(acc);
        __syncthreads();
        if (lane < 32) h1_lds[lane] = h1;
        __syncthreads();
        // GEMM2: all 64 lanes, K=32
        float acc2 = b2s;
        #pragma unroll
        for (int jj = 0; jj < 8; ++jj) {
            const float4 hv = h14[jj];
            acc2 = fmaf(hv.x, w2[4 * jj + 0], acc2);
            acc2 = fmaf(hv.y, w2[4 * jj + 1], acc2);
            acc2 = fmaf(hv.z, w2[4 * jj + 2], acc2);
            acc2 = fmaf(hv.w, w2[4 * jj + 3], acc2);
        }
        const float h2 = cosf(acc2);
        __syncthreads();
        h2_lds[lane] = h2;
        __syncthreads();
        // GEMM3: all 64 lanes, K=64
        float acc3 = b3s;
        #pragma unroll
        for (int jj = 0; jj < 16; ++jj) {
            const float4 hv = h24[jj];
            acc3 = fmaf(hv.x, w3[4 * jj + 0], acc3);
            acc3 = fmaf(hv.y, w3[4 * jj + 1], acc3);
            acc3 = fmaf(hv.z, w3[4 * jj + 2], acc3);
            acc3 = fmaf(hv.w, w3[4 * jj + 3], acc3);
        }
        return acc3;
    };

    auto emit = [&](int tt) {
        float r0 = pos * wo0, r1 = pos * wo1, r2 = pos * wo2;
        #pragma unroll
        for (int m = 1; m < 64; m <<= 1) {
            r0 += __shfl_xor(r0, m);
            r1 += __shfl_xor(r1, m);
            r2 += __shfl_xor(r2, m);
        }
        if (lane == 0) {
            *reinterpret_cast<float2*>(out + ((size_t)tt * kB + row) * 2) =
                make_float2(r0 + bo0, r1 + bo1);
            const float z = r2 + bo2;
            out[kOffP + (size_t)tt * kB + row] = 1.f / (1.f + __expf(-z));
            out[kOffL + (size_t)tt * kB + row] = 0.f;
        }
    };

    for (int tt = 0; tt < kT - 1; ++tt) {
        emit(tt);
        const float dt = dts[tt];
        const float cc = dt * (1.f / 3.f);
        const float a1 = dyn(pos, vel);
        const float p2 = fmaf(cc, vel, pos);
        const float v2 = fmaf(cc, a1, vel);
        const float a2 = dyn(p2, v2);
        const float p3 = fmaf(dt, fmaf(-1.f / 3.f, vel, v2), pos);
        const float v3 = fmaf(dt, fmaf(-1.f / 3.f, a1, a2), vel);
        const float a3 = dyn(p3, v3);
        const float p4 = fmaf(dt, vel - v2 + v3, pos);
        const float v4 = fmaf(dt, a1 - a2 + a3, vel);
        const float a4 = dyn(p4, v4);
        pos = fmaf(dt * 0.125f, vel + 3.f * (v2 + v3) + v4, pos);
        vel = fmaf(dt * 0.125f, a1 + 3.f * (a2 + a3) + a4, vel);
    }
    emit(kT - 1);
}

extern "C" void kernel_launch(void* const* d_in, const int* in_sizes, int n_in,
                              void* d_out, int out_size, void* d_ws, size_t ws_size,
                              hipStream_t stream) {
    (void)in_sizes; (void)n_in; (void)d_ws; (void)ws_size; (void)out_size;
    const float* latent = (const float*)d_in[0];
    const float* tarr   = (const float*)d_in[1];
    const float* W_l2d  = (const float*)d_in[2];
    const float* b_l2d  = (const float*)d_in[3];
    const float* W1     = (const float*)d_in[4];
    const float* b1     = (const float*)d_in[5];
    const float* W2     = (const float*)d_in[6];
    const float* b2     = (const float*)d_in[7];
    const float* W3     = (const float*)d_in[8];
    const float* b3     = (const float*)d_in[9];
    const float* W_obs  = (const float*)d_in[10];
    const float* b_obs  = (const float*)d_in[11];

    ode_seq_kernel<<<dim3(kB), dim3(64), 0, stream>>>(
        latent, tarr, W_l2d, b_l2d, W1, b1, W2, b2, W3, b3, W_obs, b_obs,
        (float*)d_out);
}

// Round 2
// 1428.497 us; speedup vs baseline: 1.5389x; 1.5389x over previous
//
#include <hip/hip_runtime.h>

namespace {
constexpr int kB = 1024;
constexpr int kT = 512;
constexpr float kScale = 3.0f * 0.15915494309189535f;  // FREQ / (2*pi)
constexpr size_t kOffP = (size_t)2 * kT * kB;          // start of traj_p
constexpr size_t kOffL = kOffP + (size_t)kT * kB;      // start of logpt
// d_ws layout in floats:
constexpr int kWsM   = 0;     // M[64][64]: col<32 = scale*(W3@W1p), col>=32 = scale*(W3@W1v)
constexpr int kWsMb  = 4096;  // mb[64]  : scale*(b3@W1p | b3@W1v)
constexpr int kWsMO  = 4160;  // MO[64][3]: W3@W_obs
constexpr int kWsMOb = 4352;  // mob[3]  : b3@W_obs
}

__global__ void setup_kernel(const float* __restrict__ W1,
                             const float* __restrict__ W3,
                             const float* __restrict__ W_obs,
                             const float* __restrict__ b3,
                             float* __restrict__ ws)
{
    const int tid = blockIdx.x * blockDim.x + threadIdx.x;
    const int nth = gridDim.x * blockDim.x;
    for (int idx = tid; idx < 64 * 64; idx += nth) {
        const int h = idx >> 6, col = idx & 63;
        const int c = col & 31, hv = col >> 5;
        float s = 0.f;
        for (int d = 0; d < 64; ++d)
            s = fmaf(W3[h * 64 + d], W1[(hv * 64 + d) * 32 + c], s);
        ws[kWsM + idx] = kScale * s;
    }
    for (int col = tid; col < 64; col += nth) {
        const int c = col & 31, hv = col >> 5;
        float s = 0.f;
        for (int d = 0; d < 64; ++d)
            s = fmaf(b3[d], W1[(hv * 64 + d) * 32 + c], s);
        ws[kWsMb + col] = kScale * s;
    }
    for (int idx = tid; idx < 64 * 3; idx += nth) {
        const int h = idx / 3, e = idx % 3;
        float s = 0.f;
        for (int d = 0; d < 64; ++d)
            s = fmaf(W3[h * 64 + d], W_obs[d * 3 + e], s);
        ws[kWsMO + idx] = s;
    }
    for (int e = tid; e < 3; e += nth) {
        float s = 0.f;
        for (int d = 0; d < 64; ++d)
            s = fmaf(b3[d], W_obs[d * 3 + e], s);
        ws[kWsMOb + e] = s;
    }
}

__global__ __launch_bounds__(64, 1) void ode_seq_kernel(
    const float* __restrict__ latent,
    const float* __restrict__ tarr,
    const float* __restrict__ W_l2d,
    const float* __restrict__ b_l2d,
    const float* __restrict__ W1,
    const float* __restrict__ b1,
    const float* __restrict__ W2,
    const float* __restrict__ b2,
    const float* __restrict__ W_obs,
    const float* __restrict__ b_obs,
    const float* __restrict__ ws,
    float* __restrict__ out)
{
    const int row  = blockIdx.x;
    const int lane = threadIdx.x;
    const int c    = lane & 31;
    const int kh   = lane >> 5;

    __shared__ __align__(16) float sbuf[128];
    __shared__ __align__(16) float h1b[32];
    __shared__ __align__(16) float h2b[64];
    __shared__ float dts[kT];

    for (int i = lane; i < kT - 1; i += 64) dts[i] = tarr[i + 1] - tarr[i];

    sbuf[lane]      = latent[row * 128 + lane];
    sbuf[64 + lane] = latent[row * 128 + 64 + lane];
    __syncthreads();

    // ---- resident weights ----
    float w2s[32];
    #pragma unroll
    for (int j = 0; j < 32; ++j) w2s[j] = kScale * W2[j * 64 + lane];
    float w3m[64];
    #pragma unroll
    for (int j = 0; j < 64; ++j) w3m[j] = ws[kWsM + j * 64 + lane];
    const float breg = ws[kWsMb + lane];
    const float mo0 = ws[kWsMO + lane * 3 + 0];
    const float mo1 = ws[kWsMO + lane * 3 + 1];
    const float mo2 = ws[kWsMO + lane * 3 + 2];
    const float mob0 = ws[kWsMOb + 0], mob1 = ws[kWsMOb + 1], mob2 = ws[kWsMOb + 2];
    const float b2s = kScale * b2[lane];
    const float bo0 = b_obs[0], bo1 = b_obs[1], bo2 = b_obs[2];

    // ---- l1c = scale*(latent @ W1l + b1), replicated to both halves ----
    float l1h = 0.f;
    #pragma unroll 8
    for (int j = 0; j < 64; ++j)
        l1h = fmaf(sbuf[kh * 64 + j], W1[(128 + kh * 64 + j) * 32 + c], l1h);
    const float l1c = kScale * (l1h + __shfl_xor(l1h, 32) + b1[c]);

    // ---- y0 = latent @ W_l2d + b_l2d ----
    float p0v = b_l2d[lane], v0v = b_l2d[64 + lane];
    #pragma unroll 4
    for (int k = 0; k < 128; ++k) {
        const float lv = sbuf[k];
        p0v = fmaf(lv, W_l2d[k * 128 + lane], p0v);
        v0v = fmaf(lv, W_l2d[k * 128 + 64 + lane], v0v);
    }

    // ---- OP = pos0@W_obs, OV = vel0@W_obs (replicated via butterfly) ----
    const float woa = W_obs[lane * 3 + 0], wob = W_obs[lane * 3 + 1], woc = W_obs[lane * 3 + 2];
    float op0 = p0v * woa, op1 = p0v * wob, op2 = p0v * woc;
    float ov0 = v0v * woa, ov1 = v0v * wob, ov2 = v0v * woc;
    #pragma unroll
    for (int m = 1; m < 64; m <<= 1) {
        op0 += __shfl_xor(op0, m); op1 += __shfl_xor(op1, m); op2 += __shfl_xor(op2, m);
        ov0 += __shfl_xor(ov0, m); ov1 += __shfl_xor(ov1, m); ov2 += __shfl_xor(ov2, m);
    }

    // ---- project state: x = scale*(pos0@W1p | vel0@W1v), V1 = scale*vel0@W1p ----
    __syncthreads();
    sbuf[lane]      = p0v;
    sbuf[64 + lane] = v0v;
    __syncthreads();
    float xacc = 0.f, vacc = 0.f;
    #pragma unroll 4
    for (int j = 0; j < 64; ++j) {
        xacc = fmaf(sbuf[kh * 64 + j], W1[(kh * 64 + j) * 32 + c], xacc);
        vacc = fmaf(sbuf[64 + j],      W1[j * 32 + c],             vacc);
    }
    float x  = kScale * xacc;
    float V1 = kScale * vacc;

    const float4* __restrict__ h14 = reinterpret_cast<const float4*>(h1b);
    const float4* __restrict__ h24 = reinterpret_cast<const float4*>(h2b);

    // dyn in projected space: returns A (= scale*acc@W1p for lo lanes, scale*acc@W1v
    // for hi lanes) and the obs projection AO = acc@W_obs (replicated).
    auto dyn = [&](float xs, float& A, float& q0, float& q1, float& q2) {
        const float pre = xs + __shfl_xor(xs, 32) + l1c;
        const float h1 = __builtin_amdgcn_cosf(pre);
        if (lane < 32) h1b[lane] = h1;
        __syncthreads();
        float a0 = b2s, a1 = 0.f, a2 = 0.f, a3 = 0.f;
        #pragma unroll
        for (int jj = 0; jj < 8; ++jj) {
            const float4 u = h14[jj];
            a0 = fmaf(u.x, w2s[4 * jj + 0], a0);
            a1 = fmaf(u.y, w2s[4 * jj + 1], a1);
            a2 = fmaf(u.z, w2s[4 * jj + 2], a2);
            a3 = fmaf(u.w, w2s[4 * jj + 3], a3);
        }
        const float h2 = __builtin_amdgcn_cosf((a0 + a1) + (a2 + a3));
        h2b[lane] = h2;
        float t0 = h2 * mo0, t1 = h2 * mo1, t2 = h2 * mo2;
        __syncthreads();
        float c0 = breg, c1 = 0.f, c2 = 0.f, c3 = 0.f;
        #pragma unroll
        for (int jj = 0; jj < 16; ++jj) {
            const float4 u = h24[jj];
            c0 = fmaf(u.x, w3m[4 * jj + 0], c0);
            c1 = fmaf(u.y, w3m[4 * jj + 1], c1);
            c2 = fmaf(u.z, w3m[4 * jj + 2], c2);
            c3 = fmaf(u.w, w3m[4 * jj + 3], c3);
        }
        #pragma unroll
        for (int m = 1; m < 64; m <<= 1) {
            t0 += __shfl_xor(t0, m);
            t1 += __shfl_xor(t1, m);
            t2 += __shfl_xor(t2, m);
        }
        A  = (c0 + c1) + (c2 + c3);
        q0 = t0 + mob0; q1 = t1 + mob1; q2 = t2 + mob2;
    };

    auto emit = [&](int tt) {
        if (lane == 0) {
            *reinterpret_cast<float2*>(out + ((size_t)tt * kB + row) * 2) =
                make_float2(op0 + bo0, op1 + bo1);
            const float z = op2 + bo2;
            out[kOffP + (size_t)tt * kB + row] = 1.f / (1.f + __expf(-z));
            out[kOffL + (size_t)tt * kB + row] = 0.f;
        }
    };

    const bool lo = (kh == 0);
    for (int tt = 0; tt < kT - 1; ++tt) {
        emit(tt);
        const float dt = dts[tt];
        const float cc = dt * (1.f / 3.f);

        float A1, u10, u11, u12; dyn(x, A1, u10, u11, u12);
        const float k1  = lo ? V1 : A1;
        const float x2  = fmaf(cc, k1, x);
        const float V1b = fmaf(cc, A1, V1);
        const float w10 = fmaf(cc, u10, ov0);
        const float w11 = fmaf(cc, u11, ov1);
        const float w12 = fmaf(cc, u12, ov2);

        float A2, u20, u21, u22; dyn(x2, A2, u20, u21, u22);
        const float k2  = lo ? V1b : A2;
        const float x3  = fmaf(dt, fmaf(-1.f / 3.f, k1, k2), x);
        const float V1c = fmaf(dt, fmaf(-1.f / 3.f, A1, A2), V1);
        const float w20 = fmaf(dt, fmaf(-1.f / 3.f, u10, u20), ov0);
        const float w21 = fmaf(dt, fmaf(-1.f / 3.f, u11, u21), ov1);
        const float w22 = fmaf(dt, fmaf(-1.f / 3.f, u12, u22), ov2);

        float A3, u30, u31, u32; dyn(x3, A3, u30, u31, u32);
        const float k3  = lo ? V1c : A3;
        const float x4  = fmaf(dt, k1 - k2 + k3, x);
        const float V1d = fmaf(dt, A1 - A2 + A3, V1);
        const float w30 = fmaf(dt, u10 - u20 + u30, ov0);
        const float w31 = fmaf(dt, u11 - u21 + u31, ov1);
        const float w32 = fmaf(dt, u12 - u22 + u32, ov2);

        float A4, u40, u41, u42; dyn(x4, A4, u40, u41, u42);
        const float k4 = lo ? V1d : A4;

        const float s = dt * 0.125f;
        x   = fmaf(s, k1 + 3.f * (k2 + k3) + k4, x);
        V1  = fmaf(s, A1 + 3.f * (A2 + A3) + A4, V1);
        op0 = fmaf(s, ov0 + 3.f * (w10 + w20) + w30, op0);
        op1 = fmaf(s, ov1 + 3.f * (w11 + w21) + w31, op1);
        op2 = fmaf(s, ov2 + 3.f * (w12 + w22) + w32, op2);
        ov0 = fmaf(s, u10 + 3.f * (u20 + u30) + u40, ov0);
        ov1 = fmaf(s, u11 + 3.f * (u21 + u31) + u41, ov1);
        ov2 = fmaf(s, u12 + 3.f * (u22 + u32) + u42, ov2);
    }
    emit(kT - 1);
}

extern "C" void kernel_launch(void* const* d_in, const int* in_sizes, int n_in,
                              void* d_out, int out_size, void* d_ws, size_t ws_size,
                              hipStream_t stream) {
    (void)in_sizes; (void)n_in; (void)ws_size; (void)out_size;
    const float* latent = (const float*)d_in[0];
    const float* tarr   = (const float*)d_in[1];
    const float* W_l2d  = (const float*)d_in[2];
    const float* b_l2d  = (const float*)d_in[3];
    const float* W1     = (const float*)d_in[4];
    const float* b1     = (const float*)d_in[5];
    const float* W2     = (const float*)d_in[6];
    const float* b2     = (const float*)d_in[7];
    const float* W3     = (const float*)d_in[8];
    const float* b3     = (const float*)d_in[9];
    const float* W_obs  = (const float*)d_in[10];
    const float* b_obs  = (const float*)d_in[11];
    float* ws = (float*)d_ws;

    setup_kernel<<<dim3(18), dim3(256), 0, stream>>>(W1, W3, W_obs, b3, ws);
    ode_seq_kernel<<<dim3(kB), dim3(64), 0, stream>>>(
        latent, tarr, W_l2d, b_l2d, W1, b1, W2, b2, W_obs, b_obs, ws,
        (float*)d_out);
}

// Round 3
// 899.118 us; speedup vs baseline: 2.4450x; 1.5888x over previous
//
#include <hip/hip_runtime.h>

namespace {
constexpr int kB = 1024;
constexpr int kT = 512;
constexpr float kScale = 3.0f * 0.15915494309189535f;  // FREQ / (2*pi)
constexpr size_t kOffP = (size_t)2 * kT * kB;          // start of traj_p
constexpr size_t kOffL = kOffP + (size_t)kT * kB;      // start of logpt
// d_ws layout in floats:
constexpr int kWsM   = 0;     // M[64][64]: col<32 = scale*(W3@W1p), col>=32 = scale*(W3@W1v)
constexpr int kWsMb  = 4096;  // mb[64]  : scale*(b3@W1p | b3@W1v)
constexpr int kWsMO  = 4160;  // MO[64][3]: W3@W_obs
constexpr int kWsMOb = 4352;  // mob[3]  : b3@W_obs
}

__global__ void setup_kernel(const float* __restrict__ W1,
                             const float* __restrict__ W3,
                             const float* __restrict__ W_obs,
                             const float* __restrict__ b3,
                             float* __restrict__ ws)
{
    const int tid = blockIdx.x * blockDim.x + threadIdx.x;
    const int nth = gridDim.x * blockDim.x;
    for (int idx = tid; idx < 64 * 64; idx += nth) {
        const int h = idx >> 6, col = idx & 63;
        const int c = col & 31, hv = col >> 5;
        float s = 0.f;
        for (int d = 0; d < 64; ++d)
            s = fmaf(W3[h * 64 + d], W1[(hv * 64 + d) * 32 + c], s);
        ws[kWsM + idx] = kScale * s;
    }
    for (int col = tid; col < 64; col += nth) {
        const int c = col & 31, hv = col >> 5;
        float s = 0.f;
        for (int d = 0; d < 64; ++d)
            s = fmaf(b3[d], W1[(hv * 64 + d) * 32 + c], s);
        ws[kWsMb + col] = kScale * s;
    }
    for (int idx = tid; idx < 64 * 3; idx += nth) {
        const int h = idx / 3, e = idx % 3;
        float s = 0.f;
        for (int d = 0; d < 64; ++d)
            s = fmaf(W3[h * 64 + d], W_obs[d * 3 + e], s);
        ws[kWsMO + idx] = s;
    }
    for (int e = tid; e < 3; e += nth) {
        float s = 0.f;
        for (int d = 0; d < 64; ++d)
            s = fmaf(b3[d], W_obs[d * 3 + e], s);
        ws[kWsMOb + e] = s;
    }
}

__device__ __forceinline__ float rl(float v, int l) {
    return __int_as_float(__builtin_amdgcn_readlane(__float_as_int(v), l));
}

__global__ __launch_bounds__(64, 1) void ode_seq_kernel(
    const float* __restrict__ latent,
    const float* __restrict__ tarr,
    const float* __restrict__ W_l2d,
    const float* __restrict__ b_l2d,
    const float* __restrict__ W1,
    const float* __restrict__ b1,
    const float* __restrict__ W2,
    const float* __restrict__ b2,
    const float* __restrict__ W_obs,
    const float* __restrict__ b_obs,
    const float* __restrict__ ws,
    float* __restrict__ out)
{
    const int row  = blockIdx.x;
    const int lane = threadIdx.x;
    const int c    = lane & 31;
    const int kh   = lane >> 5;

    __shared__ __align__(16) float sbuf[128];
    __shared__ float dts[kT];

    for (int i = lane; i < kT - 1; i += 64) dts[i] = tarr[i + 1] - tarr[i];

    sbuf[lane]      = latent[row * 128 + lane];
    sbuf[64 + lane] = latent[row * 128 + 64 + lane];
    __syncthreads();

    // ---- resident weights ----
    float w2s[32];
    #pragma unroll
    for (int j = 0; j < 32; ++j) w2s[j] = kScale * W2[j * 64 + lane];
    float w3m[64];
    #pragma unroll
    for (int j = 0; j < 64; ++j) w3m[j] = ws[kWsM + j * 64 + lane];
    const float breg = ws[kWsMb + lane];
    const float mo0 = ws[kWsMO + lane * 3 + 0];
    const float mo1 = ws[kWsMO + lane * 3 + 1];
    const float mo2 = ws[kWsMO + lane * 3 + 2];
    const float mobp0 = (lane == 0) ? ws[kWsMOb + 0] : 0.f;
    const float mobp1 = (lane == 0) ? ws[kWsMOb + 1] : 0.f;
    const float mobp2 = (lane == 0) ? ws[kWsMOb + 2] : 0.f;
    const float b2s = kScale * b2[lane];
    const float bo0 = b_obs[0], bo1 = b_obs[1], bo2 = b_obs[2];

    // ---- l1c = scale*(latent @ W1l + b1), replicated to both halves ----
    float l1h = 0.f;
    #pragma unroll 8
    for (int j = 0; j < 64; ++j)
        l1h = fmaf(sbuf[kh * 64 + j], W1[(128 + kh * 64 + j) * 32 + c], l1h);
    const float l1c = kScale * (l1h + __shfl_xor(l1h, 32) + b1[c]);

    // ---- y0 = latent @ W_l2d + b_l2d ----
    float p0v = b_l2d[lane], v0v = b_l2d[64 + lane];
    #pragma unroll 4
    for (int k = 0; k < 128; ++k) {
        const float lv = sbuf[k];
        p0v = fmaf(lv, W_l2d[k * 128 + lane], p0v);
        v0v = fmaf(lv, W_l2d[k * 128 + 64 + lane], v0v);
    }

    // ---- obs partials (per-lane; reduced only at emit) ----
    const float woa = W_obs[lane * 3 + 0], wob = W_obs[lane * 3 + 1], woc = W_obs[lane * 3 + 2];
    float op0 = p0v * woa, op1 = p0v * wob, op2 = p0v * woc;
    float ov0 = v0v * woa, ov1 = v0v * wob, ov2 = v0v * woc;

    // ---- project state: x = scale*(pos0@W1p | vel0@W1v), V1 = scale*vel0@W1p ----
    __syncthreads();
    sbuf[lane]      = p0v;
    sbuf[64 + lane] = v0v;
    __syncthreads();
    float xacc = 0.f, vacc = 0.f;
    #pragma unroll 4
    for (int j = 0; j < 64; ++j) {
        xacc = fmaf(sbuf[kh * 64 + j], W1[(kh * 64 + j) * 32 + c], xacc);
        vacc = fmaf(sbuf[64 + j],      W1[j * 32 + c],             vacc);
    }
    float x  = kScale * xacc;
    float V1 = kScale * vacc;

    // dyn in projected space, LDS-free: broadcast via v_readlane.
    auto dyn = [&](float xs, float& A, float& q0, float& q1, float& q2) {
        const float pre = xs + __shfl_xor(xs, 32) + l1c;
        const float h1 = __builtin_amdgcn_cosf(pre);
        float a0 = b2s, a1 = 0.f, a2 = 0.f, a3 = 0.f;
        #pragma unroll
        for (int j = 0; j < 8; ++j) {
            a0 = fmaf(rl(h1, 4 * j + 0), w2s[4 * j + 0], a0);
            a1 = fmaf(rl(h1, 4 * j + 1), w2s[4 * j + 1], a1);
            a2 = fmaf(rl(h1, 4 * j + 2), w2s[4 * j + 2], a2);
            a3 = fmaf(rl(h1, 4 * j + 3), w2s[4 * j + 3], a3);
        }
        const float h2 = __builtin_amdgcn_cosf((a0 + a1) + (a2 + a3));
        q0 = fmaf(h2, mo0, mobp0);
        q1 = fmaf(h2, mo1, mobp1);
        q2 = fmaf(h2, mo2, mobp2);
        float c0 = breg, c1 = 0.f, c2 = 0.f, c3 = 0.f;
        #pragma unroll
        for (int j = 0; j < 16; ++j) {
            c0 = fmaf(rl(h2, 4 * j + 0), w3m[4 * j + 0], c0);
            c1 = fmaf(rl(h2, 4 * j + 1), w3m[4 * j + 1], c1);
            c2 = fmaf(rl(h2, 4 * j + 2), w3m[4 * j + 2], c2);
            c3 = fmaf(rl(h2, 4 * j + 3), w3m[4 * j + 3], c3);
        }
        A = (c0 + c1) + (c2 + c3);
    };

    auto emit = [&](int tt) {
        float r0 = op0, r1 = op1, r2 = op2;
        #pragma unroll
        for (int m = 1; m < 64; m <<= 1) {
            r0 += __shfl_xor(r0, m);
            r1 += __shfl_xor(r1, m);
            r2 += __shfl_xor(r2, m);
        }
        if (lane == 0) {
            *reinterpret_cast<float2*>(out + ((size_t)tt * kB + row) * 2) =
                make_float2(r0 + bo0, r1 + bo1);
            const float z = r2 + bo2;
            out[kOffP + (size_t)tt * kB + row] = 1.f / (1.f + __expf(-z));
            out[kOffL + (size_t)tt * kB + row] = 0.f;
        }
    };

    const bool lo = (kh == 0);
    for (int tt = 0; tt < kT - 1; ++tt) {
        emit(tt);
        const float dt = dts[tt];
        const float cc = dt * (1.f / 3.f);

        float A1, u10, u11, u12; dyn(x, A1, u10, u11, u12);
        const float k1  = lo ? V1 : A1;
        const float x2  = fmaf(cc, k1, x);
        const float V1b = fmaf(cc, A1, V1);
        const float w10 = fmaf(cc, u10, ov0);
        const float w11 = fmaf(cc, u11, ov1);
        const float w12 = fmaf(cc, u12, ov2);

        float A2, u20, u21, u22; dyn(x2, A2, u20, u21, u22);
        const float k2  = lo ? V1b : A2;
        const float x3  = fmaf(dt, fmaf(-1.f / 3.f, k1, k2), x);
        const float V1c = fmaf(dt, fmaf(-1.f / 3.f, A1, A2), V1);
        const float w20 = fmaf(dt, fmaf(-1.f / 3.f, u10, u20), ov0);
        const float w21 = fmaf(dt, fmaf(-1.f / 3.f, u11, u21), ov1);
        const float w22 = fmaf(dt, fmaf(-1.f / 3.f, u12, u22), ov2);

        float A3, u30, u31, u32; dyn(x3, A3, u30, u31, u32);
        const float k3  = lo ? V1c : A3;
        const float x4  = fmaf(dt, k1 - k2 + k3, x);
        const float V1d = fmaf(dt, A1 - A2 + A3, V1);
        const float w30 = fmaf(dt, u10 - u20 + u30, ov0);
        const float w31 = fmaf(dt, u11 - u21 + u31, ov1);
        const float w32 = fmaf(dt, u12 - u22 + u32, ov2);

        float A4, u40, u41, u42; dyn(x4, A4, u40, u41, u42);
        const float k4 = lo ? V1d : A4;

        const float s = dt * 0.125f;
        x   = fmaf(s, k1 + 3.f * (k2 + k3) + k4, x);
        V1  = fmaf(s, A1 + 3.f * (A2 + A3) + A4, V1);
        op0 = fmaf(s, ov0 + 3.f * (w10 + w20) + w30, op0);
        op1 = fmaf(s, ov1 + 3.f * (w11 + w21) + w31, op1);
        op2 = fmaf(s, ov2 + 3.f * (w12 + w22) + w32, op2);
        ov0 = fmaf(s, u10 + 3.f * (u20 + u30) + u40, ov0);
        ov1 = fmaf(s, u11 + 3.f * (u21 + u31) + u41, ov1);
        ov2 = fmaf(s, u12 + 3.f * (u22 + u32) + u42, ov2);
    }
    emit(kT - 1);
}

extern "C" void kernel_launch(void* const* d_in, const int* in_sizes, int n_in,
                              void* d_out, int out_size, void* d_ws, size_t ws_size,
                              hipStream_t stream) {
    (void)in_sizes; (void)n_in; (void)ws_size; (void)out_size;
    const float* latent = (const float*)d_in[0];
    const float* tarr   = (const float*)d_in[1];
    const float* W_l2d  = (const float*)d_in[2];
    const float* b_l2d  = (const float*)d_in[3];
    const float* W1     = (const float*)d_in[4];
    const float* b1     = (const float*)d_in[5];
    const float* W2     = (const float*)d_in[6];
    const float* b2     = (const float*)d_in[7];
    const float* W3     = (const float*)d_in[8];
    const float* b3     = (const float*)d_in[9];
    const float* W_obs  = (const float*)d_in[10];
    const float* b_obs  = (const float*)d_in[11];
    float* ws = (float*)d_ws;

    setup_kernel<<<dim3(18), dim3(256), 0, stream>>>(W1, W3, W_obs, b3, ws);
    ode_seq_kernel<<<dim3(kB), dim3(64), 0, stream>>>(
        latent, tarr, W_l2d, b_l2d, W1, b1, W2, b2, W_obs, b_obs, ws,
        (float*)d_out);
}